// Round 8
// baseline (7242.485 us; speedup 1.0000x reference)
//
#include <hip/hip_runtime.h>
#include <math.h>

#define NDIM 64
#define PITCH 68          // chunk-row pitch in words: float4-aligned, conflict-free
#define KC 16             // columns staged per reconstruction chunk
#define MAXSWEEPS 20
#define WPB 4             // waves (= matrices) per 256-thread workgroup

// One wave (64 lanes) per 64x64 SPD matrix. Lane j owns column j in registers.
// One-sided (Hestenes) Jacobi, XOR pair ordering, alternating direction per sweep.
//
// Round-8: rounds 5/7 falsified DS-throughput as the limit (cutting DS ops at
// 124 regs left runtime at 5.9ms). Per-wave budget: 4.4M cyc alive, ~550K VALU
// + ~650K DS issue -> 72% STALL (~2500 cyc/rotation ~ 20 bpermute round trips):
// LATENCY-bound, compiler issues bpermutes in small batches with dependent
// lgkmcnt waits. Fix: software-pipeline the exchange ACROSS rotations.
// y2[i] is dead right after x2[i]'s update, and rotation k+1's partner value
// depends only on the just-updated x2[i] -> fuse in place:
//     x2[i] = c*x2[i] + s*y2[i];  y2[i] = bperm(pidx_next, x2[i]);
// (wave lockstep: the bpermute sees every lane's updated x2[i]). alpha likewise:
// update alpha first, issue its exchange before the 64-elem update loop.
// The 64-bpermute round trip now hides under the update + next dot issue; the
// serial remainder is the dot-reduce (4 packed accums, 8-deep) + Schur chain.
// Loop-carried y2 is forced live (~150 VGPR, launch_bounds(256,1)): trading
// TLP (measured useless: R1/R5/R7 invariant) for ILP that removes the stall.
// Pipeline is per-sweep (prologue fetch each sweep; 20x64 exposed bpermutes
// total, negligible). Waves never sync; per-wave LDS slices, no barriers.
typedef float v2f __attribute__((ext_vector_type(2)));

__device__ __forceinline__ v2f pk_fma(v2f a, v2f b, v2f c)
{
    v2f d;
    asm("v_pk_fma_f32 %0, %1, %2, %3" : "=v"(d) : "v"(a), "v"(b), "v"(c));
    return d;
}

__device__ __forceinline__ v2f pk_mul(v2f a, v2f b)
{
    v2f d;
    asm("v_pk_mul_f32 %0, %1, %2" : "=v"(d) : "v"(a), "v"(b));
    return d;
}

__device__ __forceinline__ float bpermf(int pidx, float v)
{
    return __int_as_float(__builtin_amdgcn_ds_bpermute(pidx, __float_as_int(v)));
}

__global__ __launch_bounds__(WPB * 64, 1)
void logeig_jacobi_kernel(const float* __restrict__ in, float* __restrict__ out)
{
    const int wid  = threadIdx.x >> 6;    // wave id within block = matrix slot
    const int lane = threadIdx.x & 63;
    const int b    = blockIdx.x * WPB + wid;
    const float* A = in  + (size_t)b * (NDIM * NDIM);
    float*       O = out + (size_t)b * (NDIM * NDIM);

    __shared__ float ldsM[WPB][KC * PITCH];   // per-wave staged columns
    __shared__ float ldsW[WPB][NDIM];         // per-wave column weights

    // stage in: column 'lane' of A, packed as 32 float2 pairs; coalesced across lanes
    v2f x2[NDIM / 2];
#pragma unroll
    for (int i = 0; i < NDIM / 2; ++i) {
        x2[i].x = A[(2 * i + 0) * NDIM + lane];
        x2[i].y = A[(2 * i + 1) * NDIM + lane];
    }

    float alpha = 0.0f;   // refreshed at each sweep start before first use

#pragma unroll 1
    for (int sweep = 0; sweep < MAXSWEEPS; ++sweep) {
        // refresh self-dot (kills incremental-update drift); packed, 2 chains
        v2f r0 = {0.f, 0.f}, r1 = {0.f, 0.f};
#pragma unroll
        for (int i = 0; i < NDIM / 2; i += 2) {
            r0 = pk_fma(x2[i],     x2[i],     r0);
            r1 = pk_fma(x2[i + 1], x2[i + 1], r1);
        }
        alpha = (r0.x + r0.y) + (r1.x + r1.y);

        const int dir = sweep & 1;

        // ---- prologue: fetch partner column & alpha for the sweep's first m ----
        const int m1    = dir ? (NDIM - 1) : 1;
        const int pidx1 = (lane ^ m1) << 2;
        v2f y2[NDIM / 2];                 // loop-carried partner column (live!)
#pragma unroll
        for (int i = 0; i < NDIM / 2; ++i) {
            y2[i].x = bpermf(pidx1, x2[i].x);
            y2[i].y = bpermf(pidx1, x2[i].y);
        }
        float aex = bpermf(pidx1, alpha);

        bool any_big = false;   // per-lane; one ballot per sweep
#pragma unroll 1
        for (int mi = 1; mi < NDIM; ++mi) {
            const int m = dir ? (NDIM - mi) : mi;  // alternate direction

            // cross dot on the PREFETCHED y2; 4 packed chains (8-deep), identical
            // ordering on both lanes of a pair -> bitwise-same gamma
            v2f g0 = {0.f, 0.f}, g1 = {0.f, 0.f}, g2 = {0.f, 0.f}, g3 = {0.f, 0.f};
#pragma unroll
            for (int i = 0; i < NDIM / 2; i += 4) {
                g0 = pk_fma(x2[i + 0], y2[i + 0], g0);
                g1 = pk_fma(x2[i + 1], y2[i + 1], g1);
                g2 = pk_fma(x2[i + 2], y2[i + 2], g2);
                g3 = pk_fma(x2[i + 3], y2[i + 3], g3);
            }
            const v2f gp = pk_fma(g0, (v2f){1.f, 1.f}, g1);   // (g0+g1)
            const v2f gq = pk_fma(g2, (v2f){1.f, 1.f}, g3);   // (g2+g3)
            const float gamma = (gp.x + gp.y) + (gq.x + gq.y);

            const bool  is_p = lane < (lane ^ m);
            const float aa = is_p ? alpha : aex;  // alpha (p's self-dot)
            const float bb = is_p ? aex : alpha;  // beta  (q's self-dot)

            // convergence detector ONLY (rel 3.2e-5 > fp32 dot noise ~5e-7);
            // does not gate the rotation -> no stagnation
            any_big = any_big || ((gamma * gamma) > (1e-9f * aa * bb));

            // Golub-Van-Loan symmetric Schur, division-free:
            //   w = 2*gamma, d = bb-aa
            //   t = sign(d)*w / (|d| + sqrt(w^2 + d^2))
            // 1e-35 floor keeps the w-denormal/d==0 corner finite; w,d identical
            // on both lanes of a pair -> bitwise-same t,c,s.
            const bool  rot = (gamma != 0.0f);
            const float w   = 2.0f * gamma;
            const float d   = bb - aa;
            const float den = fabsf(d) + __builtin_amdgcn_sqrtf(fmaf(w, w, fmaf(d, d, 1e-35f)));
            const float t   = ((d >= 0.0f) ? w : -w) * __builtin_amdgcn_rcpf(den);
            const float cc  = __builtin_amdgcn_rsqf(fmaf(t, t, 1.0f));
            const float ss  = t * cc;

            const float sgn = is_p ? -1.0f : 1.0f;  // p: x' = c x - s y ; q: x' = c x + s y
            const float c_r = rot ? cc : 1.0f;
            const float s_r = rot ? sgn * ss : 0.0f;
            const float tg  = rot ? sgn * t * gamma : 0.0f;

            v2f c2; c2.x = c_r; c2.y = c_r;
            v2f s2; s2.x = s_r; s2.y = s_r;

            alpha += tg;                   // alpha' BEFORE the update loop so its
                                           // exchange can issue early
            if (mi < NDIM - 1) {
                const int m_nx   = dir ? (NDIM - (mi + 1)) : (mi + 1);
                const int pidx_n = (lane ^ m_nx) << 2;
                aex = bpermf(pidx_n, alpha);          // hides under the update loop

                // fused update + in-place prefetch of next partner column:
                // y2[i] is dead after x2[i]'s update; the bpermute reads the
                // just-updated x2[i] from all lanes (wave lockstep).
#pragma unroll
                for (int i = 0; i < NDIM / 2; ++i) {
                    x2[i]   = pk_fma(c2, x2[i], pk_mul(s2, y2[i]));
                    y2[i].x = bpermf(pidx_n, x2[i].x);
                    y2[i].y = bpermf(pidx_n, x2[i].y);
                }
            } else {
                // last rotation of the sweep: plain update, no prefetch
#pragma unroll
                for (int i = 0; i < NDIM / 2; ++i)
                    x2[i] = pk_fma(c2, x2[i], pk_mul(s2, y2[i]));
            }
        }
        if (__ballot(any_big) == 0ull) break;   // all pairs below rel 3.2e-5 -> converged
    }

    // eigenvalue & weight: lambda = ||m||, w = log(lambda + 1e-9) / lambda^2
    v2f f0 = {0.f, 0.f}, f1 = {0.f, 0.f};
#pragma unroll
    for (int i = 0; i < NDIM / 2; i += 2) {
        f0 = pk_fma(x2[i],     x2[i],     f0);
        f1 = pk_fma(x2[i + 1], x2[i + 1], f1);
    }
    const float af  = (f0.x + f0.y) + (f1.x + f1.y);
    const float lam = __builtin_amdgcn_sqrtf(af);
    ldsW[wid][lane] = logf(lam + 1e-9f) / af;   // same-wave DS order makes this visible below

    // O[:,lane] = sum_k (w_k * m_{lane,k}) * m_{:,k}, staged KC columns at a time.
    // All LDS traffic is private to this wave; DS ops execute in program order
    // within a wave, so no barriers are needed between write and read phases.
    v2f acc2[NDIM / 2];
#pragma unroll
    for (int i = 0; i < NDIM / 2; ++i) { acc2[i].x = 0.f; acc2[i].y = 0.f; }

#pragma unroll 1
    for (int c = 0; c < NDIM; c += KC) {
        if (lane >= c && lane < c + KC) {
            float4* row = (float4*)&ldsM[wid][(lane - c) * PITCH];
#pragma unroll
            for (int t4 = 0; t4 < NDIM / 4; ++t4)
                row[t4] = make_float4(x2[2 * t4].x, x2[2 * t4].y,
                                      x2[2 * t4 + 1].x, x2[2 * t4 + 1].y);
        }
#pragma unroll 1
        for (int kk = 0; kk < KC; ++kk) {
            const float wk  = ldsW[wid][c + kk];             // broadcast
            const float mlk = ldsM[wid][kk * PITCH + lane];  // consecutive -> conflict-free
            const float zk  = wk * mlk;
            v2f zk2; zk2.x = zk; zk2.y = zk;
            const float4* rowk = (const float4*)&ldsM[wid][kk * PITCH];
#pragma unroll
            for (int t4 = 0; t4 < NDIM / 4; ++t4) {
                const float4 v = rowk[t4];              // broadcast float4
                v2f lo; lo.x = v.x; lo.y = v.y;
                v2f hi; hi.x = v.z; hi.y = v.w;
                acc2[2 * t4]     = pk_fma(zk2, lo, acc2[2 * t4]);
                acc2[2 * t4 + 1] = pk_fma(zk2, hi, acc2[2 * t4 + 1]);
            }
        }
    }

#pragma unroll
    for (int i = 0; i < NDIM / 2; ++i) {
        O[(2 * i + 0) * NDIM + lane] = acc2[i].x;   // coalesced across lanes
        O[(2 * i + 1) * NDIM + lane] = acc2[i].y;
    }
}

extern "C" void kernel_launch(void* const* d_in, const int* in_sizes, int n_in,
                              void* d_out, int out_size, void* d_ws, size_t ws_size,
                              hipStream_t stream)
{
    const float* in  = (const float*)d_in[0];
    float*       out = (float*)d_out;
    const int nmat = out_size / (NDIM * NDIM);   // 256*32 = 8192
    hipLaunchKernelGGL(logeig_jacobi_kernel, dim3(nmat / WPB), dim3(WPB * 64), 0, stream, in, out);
}

// Round 9
// 5268.158 us; speedup vs baseline: 1.3748x; 1.3748x over previous
//
#include <hip/hip_runtime.h>
#include <math.h>

#define NDIM 64
#define PITCH 68          // chunk-row pitch in words: float4-aligned, conflict-free
#define KC 16             // columns staged per reconstruction chunk
#define MAXSWEEPS 20

// One wave (64 lanes) per 64x64 SPD matrix. Lane j owns column j in registers.
// One-sided (Hestenes) Jacobi, XOR pair ordering, alternating direction per sweep.
//
// Round-9: R8 proved the across-rotation fused prefetch is CORRECT but paid
// 1.8x VALU bloat + residency loss. This round keeps the pipeline, strips the
// overhead: (1) last rotation PEELED out of the sweep loop -> branch-free
// steady-state body (R8 had a uniform if inside the unroll-1 loop: duplicated/
// if-converted code was the prime bloat suspect); (2) WPB=1 -> residency
// granularity 1 wave (law waves/CU ~ 840/VGPR: ~5 resident at ~170 regs vs 4
// with 4-wave blocks; R1 proved >=10 workgroup slots usable); (3) scalar adds
// in the gamma reduce (no (v2f){1,1} constant feeding inline asm).
// Steady state per rotation: dot on prefetched y2 -> schur -> alpha update ->
// issue aex bpermute -> fused update+prefetch (y2[i] = bperm(updated x2[i]),
// wave-lockstep-correct). 65 DS ops/rotation (minimum), latency hidden under
// the ~1200-cyc issue stream. DS-throughput floor ~3.0 ms.
typedef float v2f __attribute__((ext_vector_type(2)));

__device__ __forceinline__ v2f pk_fma(v2f a, v2f b, v2f c)
{
    v2f d;
    asm("v_pk_fma_f32 %0, %1, %2, %3" : "=v"(d) : "v"(a), "v"(b), "v"(c));
    return d;
}

__device__ __forceinline__ v2f pk_mul(v2f a, v2f b)
{
    v2f d;
    asm("v_pk_mul_f32 %0, %1, %2" : "=v"(d) : "v"(a), "v"(b));
    return d;
}

__device__ __forceinline__ float bpermf(int pidx, float v)
{
    return __int_as_float(__builtin_amdgcn_ds_bpermute(pidx, __float_as_int(v)));
}

// dot (prefetched y2) + convergence probe + division-free symmetric Schur +
// alpha update. Defines c2, s2 in the enclosing scope. Both lanes of a pair
// compute bitwise-identical gamma/t/c/s (same product order; w,d symmetric).
#define DOT_SCHUR(MVAL)                                                          \
    v2f g0 = {0.f,0.f}, g1 = {0.f,0.f}, g2 = {0.f,0.f}, g3 = {0.f,0.f};          \
    _Pragma("unroll")                                                            \
    for (int i = 0; i < NDIM / 2; i += 4) {                                      \
        g0 = pk_fma(x2[i + 0], y2[i + 0], g0);                                   \
        g1 = pk_fma(x2[i + 1], y2[i + 1], g1);                                   \
        g2 = pk_fma(x2[i + 2], y2[i + 2], g2);                                   \
        g3 = pk_fma(x2[i + 3], y2[i + 3], g3);                                   \
    }                                                                            \
    const float gamma = ((g0.x + g0.y) + (g1.x + g1.y))                          \
                      + ((g2.x + g2.y) + (g3.x + g3.y));                         \
    const bool  is_p = lane < (lane ^ (MVAL));                                   \
    const float aa = is_p ? alpha : aex;                                         \
    const float bb = is_p ? aex : alpha;                                         \
    any_big = any_big || ((gamma * gamma) > (1e-9f * aa * bb));                  \
    const bool  rot = (gamma != 0.0f);                                           \
    const float w   = 2.0f * gamma;                                              \
    const float d   = bb - aa;                                                   \
    const float den = fabsf(d) + __builtin_amdgcn_sqrtf(fmaf(w, w, fmaf(d, d, 1e-35f))); \
    const float t   = ((d >= 0.0f) ? w : -w) * __builtin_amdgcn_rcpf(den);       \
    const float cc  = __builtin_amdgcn_rsqf(fmaf(t, t, 1.0f));                   \
    const float ss  = t * cc;                                                    \
    const float sgn = is_p ? -1.0f : 1.0f;                                       \
    const float c_r = rot ? cc : 1.0f;                                           \
    const float s_r = rot ? sgn * ss : 0.0f;                                     \
    const float tg  = rot ? sgn * t * gamma : 0.0f;                              \
    v2f c2; c2.x = c_r; c2.y = c_r;                                              \
    v2f s2; s2.x = s_r; s2.y = s_r;                                              \
    alpha += tg;

__global__ __launch_bounds__(64, 1)
void logeig_jacobi_kernel(const float* __restrict__ in, float* __restrict__ out)
{
    const int b    = blockIdx.x;
    const int lane = threadIdx.x;
    const float* A = in  + (size_t)b * (NDIM * NDIM);
    float*       O = out + (size_t)b * (NDIM * NDIM);

    __shared__ float ldsM[KC * PITCH];   // staged columns (column j -> row j-c)
    __shared__ float ldsW[NDIM];         // per-column weights

    // stage in: column 'lane' of A, packed as 32 float2 pairs; coalesced across lanes
    v2f x2[NDIM / 2];
#pragma unroll
    for (int i = 0; i < NDIM / 2; ++i) {
        x2[i].x = A[(2 * i + 0) * NDIM + lane];
        x2[i].y = A[(2 * i + 1) * NDIM + lane];
    }

    float alpha = 0.0f;   // refreshed at each sweep start before first use

#pragma unroll 1
    for (int sweep = 0; sweep < MAXSWEEPS; ++sweep) {
        // refresh self-dot (kills incremental-update drift); packed, 2 chains
        v2f r0 = {0.f, 0.f}, r1 = {0.f, 0.f};
#pragma unroll
        for (int i = 0; i < NDIM / 2; i += 2) {
            r0 = pk_fma(x2[i],     x2[i],     r0);
            r1 = pk_fma(x2[i + 1], x2[i + 1], r1);
        }
        alpha = (r0.x + r0.y) + (r1.x + r1.y);

        const int dir = sweep & 1;

        // ---- prologue: fetch partner column & alpha for the sweep's first m ----
        const int m1    = dir ? (NDIM - 1) : 1;
        const int pidx1 = (lane ^ m1) << 2;
        v2f y2[NDIM / 2];                 // loop-carried partner column (live)
#pragma unroll
        for (int i = 0; i < NDIM / 2; ++i) {
            y2[i].x = bpermf(pidx1, x2[i].x);
            y2[i].y = bpermf(pidx1, x2[i].y);
        }
        float aex = bpermf(pidx1, alpha);

        bool any_big = false;   // per-lane; one ballot per sweep

        // ---- steady state: branch-free body, prefetch next rotation in the update ----
#pragma unroll 1
        for (int mi = 1; mi < NDIM - 1; ++mi) {
            const int m      = dir ? (NDIM - mi) : mi;
            const int m_nx   = dir ? (NDIM - mi - 1) : (mi + 1);
            const int pidx_n = (lane ^ m_nx) << 2;

            DOT_SCHUR(m)

            const float aexn = bpermf(pidx_n, alpha);   // issues before the update loop

            // fused update + in-place prefetch of next partner column: y2[i] is
            // dead after x2[i]'s update; the bpermute reads the just-updated
            // x2[i] from all lanes (wave lockstep).
#pragma unroll
            for (int i = 0; i < NDIM / 2; ++i) {
                x2[i]   = pk_fma(c2, x2[i], pk_mul(s2, y2[i]));
                y2[i].x = bpermf(pidx_n, x2[i].x);
                y2[i].y = bpermf(pidx_n, x2[i].y);
            }
            aex = aexn;
        }

        // ---- peeled last rotation of the sweep: no prefetch ----
        {
            const int m = dir ? 1 : (NDIM - 1);
            DOT_SCHUR(m)
#pragma unroll
            for (int i = 0; i < NDIM / 2; ++i)
                x2[i] = pk_fma(c2, x2[i], pk_mul(s2, y2[i]));
        }

        if (__ballot(any_big) == 0ull) break;   // all pairs below rel 3.2e-5 -> converged
    }

    // eigenvalue & weight: lambda = ||m||, w = log(lambda + 1e-9) / lambda^2
    v2f f0 = {0.f, 0.f}, f1 = {0.f, 0.f};
#pragma unroll
    for (int i = 0; i < NDIM / 2; i += 2) {
        f0 = pk_fma(x2[i],     x2[i],     f0);
        f1 = pk_fma(x2[i + 1], x2[i + 1], f1);
    }
    const float af  = (f0.x + f0.y) + (f1.x + f1.y);
    const float lam = __builtin_amdgcn_sqrtf(af);
    ldsW[lane] = logf(lam + 1e-9f) / af;   // same-wave DS order makes this visible below

    // O[:,lane] = sum_k (w_k * m_{lane,k}) * m_{:,k}, staged KC columns at a time.
    // All LDS traffic is private to this wave; DS ops execute in program order
    // within a wave, so no barriers are needed between write and read phases.
    v2f acc2[NDIM / 2];
#pragma unroll
    for (int i = 0; i < NDIM / 2; ++i) { acc2[i].x = 0.f; acc2[i].y = 0.f; }

#pragma unroll 1
    for (int c = 0; c < NDIM; c += KC) {
        if (lane >= c && lane < c + KC) {
            float4* row = (float4*)&ldsM[(lane - c) * PITCH];
#pragma unroll
            for (int t4 = 0; t4 < NDIM / 4; ++t4)
                row[t4] = make_float4(x2[2 * t4].x, x2[2 * t4].y,
                                      x2[2 * t4 + 1].x, x2[2 * t4 + 1].y);
        }
#pragma unroll 1
        for (int kk = 0; kk < KC; ++kk) {
            const float wk  = ldsW[c + kk];             // broadcast
            const float mlk = ldsM[kk * PITCH + lane];  // consecutive -> conflict-free
            const float zk  = wk * mlk;
            v2f zk2; zk2.x = zk; zk2.y = zk;
            const float4* rowk = (const float4*)&ldsM[kk * PITCH];
#pragma unroll
            for (int t4 = 0; t4 < NDIM / 4; ++t4) {
                const float4 v = rowk[t4];              // broadcast float4
                v2f lo; lo.x = v.x; lo.y = v.y;
                v2f hi; hi.x = v.z; hi.y = v.w;
                acc2[2 * t4]     = pk_fma(zk2, lo, acc2[2 * t4]);
                acc2[2 * t4 + 1] = pk_fma(zk2, hi, acc2[2 * t4 + 1]);
            }
        }
    }

#pragma unroll
    for (int i = 0; i < NDIM / 2; ++i) {
        O[(2 * i + 0) * NDIM + lane] = acc2[i].x;   // coalesced across lanes
        O[(2 * i + 1) * NDIM + lane] = acc2[i].y;
    }
}

extern "C" void kernel_launch(void* const* d_in, const int* in_sizes, int n_in,
                              void* d_out, int out_size, void* d_ws, size_t ws_size,
                              hipStream_t stream)
{
    const float* in  = (const float*)d_in[0];
    float*       out = (float*)d_out;
    const int nmat = out_size / (NDIM * NDIM);   // 256*32 = 8192
    hipLaunchKernelGGL(logeig_jacobi_kernel, dim3(nmat), dim3(64), 0, stream, in, out);
}